// Round 5
// baseline (334.400 us; speedup 1.0000x reference)
//
#include <hip/hip_runtime.h>
#include <hip/hip_bf16.h>

#define NROWS 65536
#define DIM   256
#define NCLS  1000
#define CPAD  1024

typedef __attribute__((ext_vector_type(8))) short bf16x8;   // 8 bf16 = 4 VGPR
typedef __attribute__((ext_vector_type(4))) float f32x4;    // MFMA C/D

// RTNE float -> bf16 bit pattern (finite inputs only)
__device__ inline unsigned short f2bf(float x) {
    unsigned int u = __builtin_bit_cast(unsigned int, x);
    unsigned int lsb = (u >> 16) & 1u;
    u += 0x7fffu + lsb;
    return (unsigned short)(u >> 16);
}

__device__ inline float bf2f(unsigned short u) {
    unsigned int v = ((unsigned int)u) << 16;
    return __builtin_bit_cast(float, v);
}

// async global->LDS, 16 B per lane, dst = wave-uniform base + lane*16
__device__ inline void gload_lds16(const void* g, void* l) {
    __builtin_amdgcn_global_load_lds(
        (const __attribute__((address_space(1))) unsigned int*)g,
        (__attribute__((address_space(3))) unsigned int*)l, 16, 0, 0);
}

// K1: 8 rows per wave, 4-row batched pipeline (R9). Also zeroes the
// sums/counts/acc/done scratch (stream-ordered before K2 needs it).
__global__ __launch_bounds__(256) void k_norm_acc(
    const float* __restrict__ emb, unsigned short* __restrict__ e,
    float* __restrict__ sums, unsigned int* __restrict__ counts,
    float* __restrict__ acc, unsigned int* __restrict__ done)
{
    const int tid = threadIdx.x;
    const int bid = blockIdx.x;
    // zero scratch: 2048 blocks x 128 floats = CPAD*DIM sums
    if (tid < 128) sums[bid * 128 + tid] = 0.0f;
    if (bid < 16 && tid < 64) counts[bid * 64 + tid] = 0u;   // 1024 counts
    if (bid == 0 && tid == 0) { *acc = 0.0f; *done = 0u; }

    const int wave = tid >> 6, lane = tid & 63;
    const int w = bid * 4 + wave;                 // 8192 waves, 8 rows each

    #pragma unroll
    for (int i = 0; i < 2; ++i) {
        const int rbase = w * 8 + i * 4;
        float4 v[4];
        #pragma unroll
        for (int r = 0; r < 4; ++r)
            v[r] = ((const float4*)(emb + (size_t)(rbase + r) * DIM))[lane];
        float ss[4];
        #pragma unroll
        for (int r = 0; r < 4; ++r)
            ss[r] = v[r].x*v[r].x + v[r].y*v[r].y + v[r].z*v[r].z + v[r].w*v[r].w;
        #pragma unroll
        for (int off = 1; off < 64; off <<= 1) {
            #pragma unroll
            for (int r = 0; r < 4; ++r) ss[r] += __shfl_xor(ss[r], off);
        }
        #pragma unroll
        for (int r = 0; r < 4; ++r) {
            float inv = 1.0f / fmaxf(sqrtf(ss[r]), 1e-12f);
            ushort4 u;
            u.x = f2bf(v[r].x * inv); u.y = f2bf(v[r].y * inv);
            u.z = f2bf(v[r].z * inv); u.w = f2bf(v[r].w * inv);
            ((ushort4*)(e + (size_t)(rbase + r) * DIM))[lane] = u;
        }
    }
}

// K2: partial class sums, 2000 blocks = 1000 classes x 2 row-halves
// (~31 waves/CU: the gather while-loops are latency-bound — R9 proved TLP
// is what they need). Ballot-scan half the labels, wave-cooperative row
// gathers, flush via one fp32 global atomic per dim + one counts atomic.
__global__ __launch_bounds__(256) void k_gather_partial(
    const unsigned short* __restrict__ e, const int* __restrict__ labels,
    float* __restrict__ sums, unsigned int* __restrict__ counts)
{
    const int c   = blockIdx.x >> 1;       // 0..999
    const int h   = blockIdx.x & 1;        // row half
    const int tid = threadIdx.x;
    const int wave = tid >> 6, lane = tid & 63;

    __shared__ float part[4][DIM];
    __shared__ unsigned int cnt_s[4];

    const int base = h * (NROWS / 2);
    float a0 = 0.f, a1 = 0.f, a2 = 0.f, a3 = 0.f;
    unsigned int cnt = 0;

    for (int it = 0; it < (NROWS / 2) / 256 / 8; ++it) {   // 16 iterations
        int lb[8];
        #pragma unroll
        for (int u = 0; u < 8; ++u)
            lb[u] = labels[base + (it * 8 + u) * 256 + wave * 64 + lane];
        #pragma unroll
        for (int u = 0; u < 8; ++u) {
            unsigned long long m = __ballot(lb[u] == c);
            cnt += (unsigned int)__popcll(m);
            int rb = base + (it * 8 + u) * 256 + wave * 64;
            while (m) {
                int b = __ffsll((long long)m) - 1;  m &= m - 1;
                ushort4 v = ((const ushort4*)(e + (size_t)(rb + b) * DIM))[lane];
                a0 += bf2f(v.x); a1 += bf2f(v.y); a2 += bf2f(v.z); a3 += bf2f(v.w);
            }
        }
    }
    ((float4*)part[wave])[lane] = make_float4(a0, a1, a2, a3);
    if (lane == 0) cnt_s[wave] = cnt;
    __syncthreads();

    float s = part[0][tid] + part[1][tid] + part[2][tid] + part[3][tid];
    atomicAdd(&sums[(size_t)c * DIM + tid], s);
    if (tid == 0)
        atomicAdd(&counts[c], cnt_s[0] + cnt_s[1] + cnt_s[2] + cnt_s[3]);
}

// K3: one wave per class (all CPAD): center = sum/max(cnt,1), fold
// 1/max(||c||,1e-8), store bf16. Phantoms: sums=0,counts=0 -> cs=0.
__global__ __launch_bounds__(256) void k_centers(
    const float* __restrict__ sums, const unsigned int* __restrict__ counts,
    unsigned short* __restrict__ cs)
{
    int gid  = blockIdx.x * 256 + threadIdx.x;
    int c    = gid >> 6;          // wave-uniform
    int lane = gid & 63;
    float4 v = ((const float4*)(sums + (size_t)c * DIM))[lane];
    float ic = 1.0f / fmaxf((float)counts[c], 1.0f);
    v.x *= ic; v.y *= ic; v.z *= ic; v.w *= ic;
    float ss = v.x*v.x + v.y*v.y + v.z*v.z + v.w*v.w;
    #pragma unroll
    for (int off = 1; off < 64; off <<= 1) ss += __shfl_xor(ss, off);
    float sc = 1.0f / fmaxf(sqrtf(ss), 1e-8f);
    ushort4 u;
    u.x = f2bf(v.x * sc); u.y = f2bf(v.y * sc);
    u.z = f2bf(v.z * sc); u.w = f2bf(v.w * sc);
    ((ushort4*)(cs + (size_t)c * DIM))[lane] = u;
}

// K4 v6 (R14). R13 post-mortem: VGPR_Count was pinned at EXACTLY 128 in
// both R12 and R13 regardless of accumulator size, with massive scratch
// (WRITE_SIZE 160 MB). Diagnosis: __launch_bounds__'s 2nd arg acts as
// min BLOCKS/CU (CUDA semantics) on this toolchain: (512,2) -> 2 blocks
// x 8 waves = 16 waves/CU = 4 waves/SIMD -> hard cap 512/4 = 128 VGPR.
// Evidence: R1 (256,2)->cap 256, used 108 (no spill); R2 (256,1)->cap
// 512, used 228 (no spill); R12/R13 (512,2)->cap 128, spilled ~1 KB/thr.
// Fix (single variable vs R13): __launch_bounds__(512, 1) -> 1 block/CU
// = 8 waves = 2/SIMD -> cap 256. v5 live set ~155 regs fits with ~100
// regs slack for the scheduler to hoist B loads (only 2 waves/SIMD).
// Structure (unchanged from R13):
//  - 512 threads = 8 waves (2/SIMD), TMB=256 rows, grid=256 = 1
//    block/CU (128 KB LDS forces it anyway), zero tail.
//  - A staged ONCE into LDS via glds, XOR-swizzle (verified absmax=0,
//    0 bank conflicts). One __syncthreads() total.
//  - B fragments straight from global (cs = 512 KB, L1/L2-hot). ZERO
//    barriers / vmcnt / sched_barriers in the main loop.
//  - Per class tile: two 32-col halves, accf[8][2]=64 regs live.
// Floor estimate per CU: MFMA 9.9k cyc, LDS 16.4k cyc, B-from-L2 ~8k
// cyc, overlapped -> ~7-9 us.
#define TMB 256
#define TCB 256

__global__ __launch_bounds__(512, 1) void k_loss_mfma(
    const unsigned short* __restrict__ e, const unsigned short* __restrict__ cs,
    const int* __restrict__ labels, float* __restrict__ acc,
    unsigned int* __restrict__ done, float* __restrict__ out)
{
    __shared__ __align__(16) unsigned short a_s[4][TMB * 64];  // 128 KB
    __shared__ float red_s[8];

    const int tid  = threadIdx.x;
    const int row0 = blockIdx.x * TMB;
    const int wave = tid >> 6, lane = tid & 63;
    const int wm = wave >> 2, wn = wave & 3;   // 2M x 4N wave grid
    const int l16 = lane & 15, q = lane >> 4;
    const int st_r = lane >> 3;                // staging row within 8-row chunk
    const int st_s = (lane & 7) ^ st_r;        // XOR-swizzled source slice

    // prologue: stage all 4 A panels (rows row0..row0+255) via glds.
    // 128 glds total, 16 per wave. Issued first to hide HBM/L3 latency.
    #pragma unroll
    for (int kc = 0; kc < 4; ++kc)
        #pragma unroll
        for (int ch = 0; ch < 4; ++ch) {
            int c2 = wave * 4 + ch;            // chunk = 8 rows x 64 bf16
            gload_lds16(&e[(size_t)(row0 + c2*8 + st_r) * DIM + kc*64 + st_s*8],
                        &a_s[kc][c2 * 512]);
        }

    // labels for this lane's 32 output rows (C/D row = q*4 + rg)
    int labv[32];
    #pragma unroll
    for (int mi = 0; mi < 8; ++mi)
        #pragma unroll
        for (int rg = 0; rg < 4; ++rg)
            labv[mi*4 + rg] = labels[row0 + wm*128 + mi*16 + q*4 + rg];

    __syncthreads();   // the ONLY barrier: A panels + labv in flight done

    float la_bulk = 0.0f, la_corr = 0.0f;
    const float KN = 1.0f / 999.0f;

    for (int cb = 0; cb < CPAD / TCB; ++cb) {
        #pragma unroll
        for (int nh = 0; nh < 2; ++nh) {
            f32x4 accf[8][2];
            #pragma unroll
            for (int mi = 0; mi < 8; ++mi)
                #pragma unroll
                for (int ni = 0; ni < 2; ++ni)
                    accf[mi][ni] = (f32x4){0.f, 0.f, 0.f, 0.f};

            // B base for this wave's 32-col half-slice of class tile cb
            const unsigned short* bbase =
                cs + (size_t)(cb*TCB + wn*64 + nh*32 + l16) * DIM + q * 8;

            #pragma unroll
            for (int kc = 0; kc < 4; ++kc) {
                #pragma unroll
                for (int kk = 0; kk < 2; ++kk) {
                    bf16x8 bfr[2];
                    #pragma unroll
                    for (int ni = 0; ni < 2; ++ni)
                        bfr[ni] = *(const bf16x8*)(bbase + ni*16*DIM + kc*64 + kk*32);
                    bf16x8 afv[8];
                    #pragma unroll
                    for (int mi = 0; mi < 8; ++mi) {
                        int rowA = wm*128 + mi*16 + l16;
                        afv[mi] = *(const bf16x8*)&a_s[kc][
                            rowA*64 + (((kk*4 + q) ^ (rowA & 7)) * 8)];
                    }
                    #pragma unroll
                    for (int mi = 0; mi < 8; ++mi)
                        #pragma unroll
                        for (int ni = 0; ni < 2; ++ni)
                            accf[mi][ni] = __builtin_amdgcn_mfma_f32_16x16x32_bf16(
                                afv[mi], bfr[ni], accf[mi][ni], 0, 0, 0);
                }
            }

            // epilogue for this half: C/D col = cb*256 + wn*64 + nh*32
            // + ni*16 + l16, row = wm*128 + mi*16 + q*4 + rg.
            #pragma unroll
            for (int mi = 0; mi < 8; ++mi)
                #pragma unroll
                for (int rg = 0; rg < 4; ++rg) {
                    #pragma unroll
                    for (int ni = 0; ni < 2; ++ni) {
                        float t = 1.0f - accf[mi][ni][rg];
                        la_bulk += t * t;
                    }
                    int lr = labv[mi*4 + rg] - cb*TCB - wn*64 - nh*32 - l16;
                    if ((lr & ~16) == 0) {     // lr in {0,16}
                        float sv = (lr >> 4) ? accf[mi][1][rg] : accf[mi][0][rg];
                        float t = 1.0f - sv;
                        la_corr += t * t;
                    }
                }
        }
    }

    // block reduction + fused finalization via atomic ticket
    float la = la_bulk * KN + la_corr * (1.0f - KN);
    #pragma unroll
    for (int off = 32; off >= 1; off >>= 1) la += __shfl_xor(la, off);
    if (lane == 0) red_s[wave] = la;
    __syncthreads();
    if (tid == 0) {
        atomicAdd(acc, red_s[0] + red_s[1] + red_s[2] + red_s[3]
                     + red_s[4] + red_s[5] + red_s[6] + red_s[7]);
        __threadfence();
        unsigned int t = atomicAdd(done, 1u);
        if (t == (unsigned int)(NROWS / TMB) - 1u) {
            float v = atomicAdd(acc, 0.0f);    // atomic read: all adds visible
            out[0] = v * (1.0f / (float)NROWS) - 24.0f * (1.0f / 999.0f);
        }
    }
}

extern "C" void kernel_launch(void* const* d_in, const int* in_sizes, int n_in,
                              void* d_out, int out_size, void* d_ws, size_t ws_size,
                              hipStream_t stream)
{
    const float* emb    = (const float*)d_in[0];
    const int*   labels = (const int*)d_in[1];
    float*       out    = (float*)d_out;
    char*        ws     = (char*)d_ws;

    const size_t OFF_CS   = (size_t)NROWS * DIM * 2;            // e: 32 MB
    const size_t OFF_SUMS = OFF_CS + (size_t)CPAD * DIM * 2;    // cs: 512 KB
    const size_t OFF_CNT  = OFF_SUMS + (size_t)CPAD * DIM * 4;  // sums: 1 MB
    const size_t OFF_ACC  = OFF_CNT + (size_t)CPAD * 4;         // counts: 4 KB
    const size_t OFF_DONE = OFF_ACC + 16;

    unsigned short* e      = (unsigned short*)ws;
    unsigned short* cs     = (unsigned short*)(ws + OFF_CS);
    float*          sums   = (float*)(ws + OFF_SUMS);
    unsigned int*   counts = (unsigned int*)(ws + OFF_CNT);
    float*          acc    = (float*)(ws + OFF_ACC);
    unsigned int*   done   = (unsigned int*)(ws + OFF_DONE);

    k_norm_acc      <<<NROWS / 32, 256, 0, stream>>>(emb, e, sums, counts, acc, done);
    k_gather_partial<<<NCLS * 2, 256, 0, stream>>>(e, labels, sums, counts);
    k_centers       <<<CPAD / 4, 256, 0, stream>>>(sums, counts, cs);
    k_loss_mfma     <<<NROWS / TMB, 512, 0, stream>>>(e, cs, labels, acc, done, out);
}

// Round 6
// 199.221 us; speedup vs baseline: 1.6785x; 1.6785x over previous
//
#include <hip/hip_runtime.h>
#include <hip/hip_bf16.h>

#define NROWS 65536
#define DIM   256
#define NCLS  1000
#define CPAD  1024

typedef __attribute__((ext_vector_type(8))) short bf16x8;   // 8 bf16 = 4 VGPR
typedef __attribute__((ext_vector_type(4))) float f32x4;    // MFMA C/D

// RTNE float -> bf16 bit pattern (finite inputs only)
__device__ inline unsigned short f2bf(float x) {
    unsigned int u = __builtin_bit_cast(unsigned int, x);
    unsigned int lsb = (u >> 16) & 1u;
    u += 0x7fffu + lsb;
    return (unsigned short)(u >> 16);
}

__device__ inline float bf2f(unsigned short u) {
    unsigned int v = ((unsigned int)u) << 16;
    return __builtin_bit_cast(float, v);
}

// async global->LDS, 16 B per lane, dst = wave-uniform base + lane*16
__device__ inline void gload_lds16(const void* g, void* l) {
    __builtin_amdgcn_global_load_lds(
        (const __attribute__((address_space(1))) unsigned int*)g,
        (__attribute__((address_space(3))) unsigned int*)l, 16, 0, 0);
}

// K1: 8 rows per wave, 4-row batched pipeline (R9). Also zeroes the
// sums/counts/acc/done scratch (stream-ordered before K2 needs it).
__global__ __launch_bounds__(256) void k_norm_acc(
    const float* __restrict__ emb, unsigned short* __restrict__ e,
    float* __restrict__ sums, unsigned int* __restrict__ counts,
    float* __restrict__ acc, unsigned int* __restrict__ done)
{
    const int tid = threadIdx.x;
    const int bid = blockIdx.x;
    // zero scratch: 2048 blocks x 128 floats = CPAD*DIM sums
    if (tid < 128) sums[bid * 128 + tid] = 0.0f;
    if (bid < 16 && tid < 64) counts[bid * 64 + tid] = 0u;   // 1024 counts
    if (bid == 0 && tid == 0) { *acc = 0.0f; *done = 0u; }

    const int wave = tid >> 6, lane = tid & 63;
    const int w = bid * 4 + wave;                 // 8192 waves, 8 rows each

    #pragma unroll
    for (int i = 0; i < 2; ++i) {
        const int rbase = w * 8 + i * 4;
        float4 v[4];
        #pragma unroll
        for (int r = 0; r < 4; ++r)
            v[r] = ((const float4*)(emb + (size_t)(rbase + r) * DIM))[lane];
        float ss[4];
        #pragma unroll
        for (int r = 0; r < 4; ++r)
            ss[r] = v[r].x*v[r].x + v[r].y*v[r].y + v[r].z*v[r].z + v[r].w*v[r].w;
        #pragma unroll
        for (int off = 1; off < 64; off <<= 1) {
            #pragma unroll
            for (int r = 0; r < 4; ++r) ss[r] += __shfl_xor(ss[r], off);
        }
        #pragma unroll
        for (int r = 0; r < 4; ++r) {
            float inv = 1.0f / fmaxf(sqrtf(ss[r]), 1e-12f);
            ushort4 u;
            u.x = f2bf(v[r].x * inv); u.y = f2bf(v[r].y * inv);
            u.z = f2bf(v[r].z * inv); u.w = f2bf(v[r].w * inv);
            ((ushort4*)(e + (size_t)(rbase + r) * DIM))[lane] = u;
        }
    }
}

// K2 v3 (R15): 250 class-groups x 8 row-slices = 2000 blocks (same TLP
// as v2: the gather while-loops are latency-bound and need waves).
// Each block scans its slice's 8192 labels ONCE for FOUR classes:
// label traffic 262 MB -> 64 MB. Gather volume unchanged (disjoint
// matches). Ballot is wave-uniform -> cnt[] is uniform; flush uses
// static indices only (rule: no runtime-indexed register arrays).
__global__ __launch_bounds__(256) void k_gather_partial(
    const unsigned short* __restrict__ e, const int* __restrict__ labels,
    float* __restrict__ sums, unsigned int* __restrict__ counts)
{
    const int grp = blockIdx.x >> 3;       // 0..249 -> classes grp*4..+3
    const int sl  = blockIdx.x & 7;        // row slice
    const int c0  = grp * 4;
    const int tid = threadIdx.x;
    const int wave = tid >> 6, lane = tid & 63;

    __shared__ float part[4][4][DIM];      // [wave][class][dim] 16 KB
    __shared__ unsigned int cnt_s[4][4];

    const int base = sl * (NROWS / 8);     // 8192 rows per slice
    float a[4][4];                         // [class][dim4]
    #pragma unroll
    for (int cl = 0; cl < 4; ++cl)
        #pragma unroll
        for (int d = 0; d < 4; ++d) a[cl][d] = 0.0f;
    unsigned int cnt[4] = {0u, 0u, 0u, 0u};

    for (int it = 0; it < (NROWS / 8) / 256 / 8; ++it) {   // 4 iterations
        int lb[8];
        #pragma unroll
        for (int u = 0; u < 8; ++u)
            lb[u] = labels[base + (it * 8 + u) * 256 + wave * 64 + lane];
        #pragma unroll
        for (int u = 0; u < 8; ++u) {
            int rb = base + (it * 8 + u) * 256 + wave * 64;
            #pragma unroll
            for (int cl = 0; cl < 4; ++cl) {
                unsigned long long m = __ballot(lb[u] == c0 + cl);
                cnt[cl] += (unsigned int)__popcll(m);
                while (m) {
                    int b = __ffsll((long long)m) - 1;  m &= m - 1;
                    ushort4 v = ((const ushort4*)(e + (size_t)(rb + b) * DIM))[lane];
                    a[cl][0] += bf2f(v.x); a[cl][1] += bf2f(v.y);
                    a[cl][2] += bf2f(v.z); a[cl][3] += bf2f(v.w);
                }
            }
        }
    }
    #pragma unroll
    for (int cl = 0; cl < 4; ++cl)
        ((float4*)part[wave][cl])[lane] =
            make_float4(a[cl][0], a[cl][1], a[cl][2], a[cl][3]);
    if (lane == 0) {
        cnt_s[wave][0] = cnt[0]; cnt_s[wave][1] = cnt[1];
        cnt_s[wave][2] = cnt[2]; cnt_s[wave][3] = cnt[3];
    }
    __syncthreads();

    #pragma unroll
    for (int cl = 0; cl < 4; ++cl) {
        float s = part[0][cl][tid] + part[1][cl][tid]
                + part[2][cl][tid] + part[3][cl][tid];
        atomicAdd(&sums[(size_t)(c0 + cl) * DIM + tid], s);
    }
    if (tid < 4)
        atomicAdd(&counts[c0 + tid], cnt_s[0][tid] + cnt_s[1][tid]
                                   + cnt_s[2][tid] + cnt_s[3][tid]);
}

// K3: one wave per class (all CPAD): center = sum/max(cnt,1), fold
// 1/max(||c||,1e-8), store bf16. Phantoms: sums=0,counts=0 -> cs=0.
__global__ __launch_bounds__(256) void k_centers(
    const float* __restrict__ sums, const unsigned int* __restrict__ counts,
    unsigned short* __restrict__ cs)
{
    int gid  = blockIdx.x * 256 + threadIdx.x;
    int c    = gid >> 6;          // wave-uniform
    int lane = gid & 63;
    float4 v = ((const float4*)(sums + (size_t)c * DIM))[lane];
    float ic = 1.0f / fmaxf((float)counts[c], 1.0f);
    v.x *= ic; v.y *= ic; v.z *= ic; v.w *= ic;
    float ss = v.x*v.x + v.y*v.y + v.z*v.z + v.w*v.w;
    #pragma unroll
    for (int off = 1; off < 64; off <<= 1) ss += __shfl_xor(ss, off);
    float sc = 1.0f / fmaxf(sqrtf(ss), 1e-8f);
    ushort4 u;
    u.x = f2bf(v.x * sc); u.y = f2bf(v.y * sc);
    u.z = f2bf(v.z * sc); u.w = f2bf(v.w * sc);
    ((ushort4*)(cs + (size_t)c * DIM))[lane] = u;
}

// K4 v8 (R15). Register model (fits ALL R1-R14 data): launch_bounds 2nd
// arg = min waves/EU, clamped to >= blockWaves/4; unified VGPR+AGPR
// budget 512/EU. 512-thread blocks can't hold this kernel (R12-R14
// spilled to exactly 256 total) -> back to the R1-proven 256-thread
// geometry (108 VGPR + 64 AGPR, 48 us, MfmaUtil 26%), and attack R1's
// diagnosed stall (barrier phase-lock) with CROSS-BLOCK stagger:
//  - TMB 128 -> 64: grid 1024 blocks; wave = 16 rows (af 32 VGPR,
//    accf[8] = 32 AGPR, total ~120 regs).
//  - B pipeline depth 4 -> 3 (b_s[3], 48 KB LDS) with counted
//    "s_waitcnt vmcnt(4)" (stage t+2 in flight) -> 3 resident
//    blocks/CU = 12 waves = 3/EU (__launch_bounds__(256,3), cap 170).
//    Three barrier-INDEPENDENT blocks fill each other's stage/barrier
//    stalls (R10/R11 showed one barrier group serializes pipes).
//  - Per step per CU: MFMA 12 waves x 16 = 931 cyc > LDS reads 768 cyc
//    -> MFMA-dominant. Floor 16.6 us.
//  - Stages run past the end with &(CPAD-1) source wrap (junk lands in
//    buffers never read again) so vmcnt(4) is uniform for every step.
//  - Labels packed 2/int (4 labels -> labp[2]) to shave VGPRs.
#define TMB 64
#define TCB 128

__global__ __launch_bounds__(256, 3) void k_loss_mfma(
    const unsigned short* __restrict__ e, const unsigned short* __restrict__ cs,
    const int* __restrict__ labels, float* __restrict__ acc,
    unsigned int* __restrict__ done, float* __restrict__ out)
{
    __shared__ __align__(16) unsigned short b_s[3][TCB * 64];  // 48 KB
    __shared__ float red_s[4];

    const int tid  = threadIdx.x;
    const int row0 = blockIdx.x * TMB;
    const int wave = tid >> 6, lane = tid & 63;
    const int l16 = lane & 15, q = lane >> 4;
    const int st_r = lane >> 3;                // staging row within 8-row chunk
    const int st_s = (lane & 7) ^ st_r;        // XOR-swizzled source slice

    // prologue: stage steps t=0 -> buf0, t=1 -> buf1 (8 glds/wave total? 2x4)
    #pragma unroll
    for (int pt = 0; pt < 2; ++pt)
        #pragma unroll
        for (int ch = 0; ch < 4; ++ch) {
            int chunk = wave * 4 + ch;         // 16 chunks x 8 rows = TCB
            gload_lds16(&cs[(size_t)(chunk*8 + st_r) * DIM + pt*64 + st_s*8],
                        &b_s[pt][chunk * 512]);
        }

    // labels for this lane's 4 output rows, packed 2 per int
    int labp[2];
    #pragma unroll
    for (int p = 0; p < 2; ++p) {
        int rr = row0 + wave*16 + q*4 + p*2;
        labp[p] = labels[rr] | (labels[rr + 1] << 16);
    }

    // A fragments in registers (16 rows x 256 dims), indices compile-time
    bf16x8 af[4][2];
    {
        const unsigned short* pa =
            e + (size_t)(row0 + wave*16 + l16) * DIM + q * 8;
        #pragma unroll
        for (int kc = 0; kc < 4; ++kc)
            #pragma unroll
            for (int kk = 0; kk < 2; ++kk)
                af[kc][kk] = *(const bf16x8*)(pa + kc*64 + kk*32);
    }

    __syncthreads();   // full drain: prologue stages + labp + af done

    float la_bulk = 0.0f, la_corr = 0.0f;
    const float KN = 1.0f / 999.0f;

    int cur0 = 0;                              // buf index of step cb*4 (mod 3)
    for (int cb = 0; cb < CPAD / TCB; ++cb) {
        f32x4 accf[8];
        #pragma unroll
        for (int ni = 0; ni < 8; ++ni) accf[ni] = (f32x4){0.f, 0.f, 0.f, 0.f};

        #pragma unroll
        for (int kc = 0; kc < 4; ++kc) {
            // step t = cb*4 + kc reads b_s[cu]; stage t+2 -> b_s[sg]
            int cu = cur0 + kc;     if (cu >= 3) cu -= 3; if (cu >= 3) cu -= 3;
            int sg = cur0 + kc + 2; if (sg >= 3) sg -= 3; if (sg >= 3) sg -= 3;

            __builtin_amdgcn_sched_barrier(0);
            // own stage(t) (issued at t-2) done; <=4 younger (t+1) remain
            asm volatile("s_waitcnt vmcnt(4)" ::: "memory");
            __builtin_amdgcn_s_barrier();
            __builtin_amdgcn_sched_barrier(0);

            {   // stage step t+2 (source wraps past the end: junk is safe)
                const int t2  = cb * 4 + kc + 2;
                const int cb2 = t2 >> 2, kc2 = t2 & 3;
                #pragma unroll
                for (int ch = 0; ch < 4; ++ch) {
                    int chunk = wave * 4 + ch;
                    int crow  = (cb2 * TCB + chunk * 8 + st_r) & (CPAD - 1);
                    gload_lds16(&cs[(size_t)crow * DIM + kc2*64 + st_s*8],
                                &b_s[sg][chunk * 512]);
                }
            }

            const unsigned short* bs = b_s[cu];
            #pragma unroll
            for (int kk = 0; kk < 2; ++kk) {
                bf16x8 bfr[8];
                #pragma unroll
                for (int ni = 0; ni < 8; ++ni) {
                    int rowB = ni * 16 + l16;
                    bfr[ni] = *(const bf16x8*)&bs[rowB * 64 + (((kk*4 + q) ^ (rowB & 7)) * 8)];
                }
                #pragma unroll
                for (int ni = 0; ni < 8; ++ni)
                    accf[ni] = __builtin_amdgcn_mfma_f32_16x16x32_bf16(
                        af[kc][kk], bfr[ni], accf[ni], 0, 0, 0);
            }
        }

        // epilogue: C/D col = cb*128 + ni*16 + l16, row = wave*16 + q*4 + rg
        #pragma unroll
        for (int rg = 0; rg < 4; ++rg) {
            #pragma unroll
            for (int ni = 0; ni < 8; ++ni) {
                float t = 1.0f - accf[ni][rg];
                la_bulk += t * t;
            }
            int lv = (labp[rg >> 1] >> ((rg & 1) * 16)) & 0xffff;
            int lr = lv - cb*TCB - l16;
            if ((lr & ~112) == 0) {            // lr in {0,16,...,112}
                int nih = lr >> 4;
                float sv = (nih & 4)
                    ? ((nih & 2) ? ((nih & 1) ? accf[7][rg] : accf[6][rg])
                                 : ((nih & 1) ? accf[5][rg] : accf[4][rg]))
                    : ((nih & 2) ? ((nih & 1) ? accf[3][rg] : accf[2][rg])
                                 : ((nih & 1) ? accf[1][rg] : accf[0][rg]));
                float t = 1.0f - sv;
                la_corr += t * t;
            }
        }
        cur0 = (cur0 + 1 == 3) ? 0 : cur0 + 1;   // 4 steps ≡ +1 (mod 3)
    }

    // block reduction + fused finalization via atomic ticket
    float la = la_bulk * KN + la_corr * (1.0f - KN);
    #pragma unroll
    for (int off = 32; off >= 1; off >>= 1) la += __shfl_xor(la, off);
    if (lane == 0) red_s[wave] = la;
    __syncthreads();
    if (tid == 0) {
        atomicAdd(acc, red_s[0] + red_s[1] + red_s[2] + red_s[3]);
        __threadfence();
        unsigned int t = atomicAdd(done, 1u);
        if (t == (unsigned int)(NROWS / TMB) - 1u) {
            float v = atomicAdd(acc, 0.0f);    // atomic read: all adds visible
            out[0] = v * (1.0f / (float)NROWS) - 24.0f * (1.0f / 999.0f);
        }
    }
}

extern "C" void kernel_launch(void* const* d_in, const int* in_sizes, int n_in,
                              void* d_out, int out_size, void* d_ws, size_t ws_size,
                              hipStream_t stream)
{
    const float* emb    = (const float*)d_in[0];
    const int*   labels = (const int*)d_in[1];
    float*       out    = (float*)d_out;
    char*        ws     = (char*)d_ws;

    const size_t OFF_CS   = (size_t)NROWS * DIM * 2;            // e: 32 MB
    const size_t OFF_SUMS = OFF_CS + (size_t)CPAD * DIM * 2;    // cs: 512 KB
    const size_t OFF_CNT  = OFF_SUMS + (size_t)CPAD * DIM * 4;  // sums: 1 MB
    const size_t OFF_ACC  = OFF_CNT + (size_t)CPAD * 4;         // counts: 4 KB
    const size_t OFF_DONE = OFF_ACC + 16;

    unsigned short* e      = (unsigned short*)ws;
    unsigned short* cs     = (unsigned short*)(ws + OFF_CS);
    float*          sums   = (float*)(ws + OFF_SUMS);
    unsigned int*   counts = (unsigned int*)(ws + OFF_CNT);
    float*          acc    = (float*)(ws + OFF_ACC);
    unsigned int*   done   = (unsigned int*)(ws + OFF_DONE);

    k_norm_acc      <<<NROWS / 32, 256, 0, stream>>>(emb, e, sums, counts, acc, done);
    k_gather_partial<<<NCLS * 2, 256, 0, stream>>>(e, labels, sums, counts);
    k_centers       <<<CPAD / 4, 256, 0, stream>>>(sums, counts, cs);
    k_loss_mfma     <<<NROWS / TMB, 256, 0, stream>>>(e, cs, labels, acc, done, out);
}